// Round 1
// baseline (3309.063 us; speedup 1.0000x reference)
//
#include <hip/hip_runtime.h>

// Problem constants: B=1, C=2, H=W=64, m=8192, mk=64, K1=K2=36, K3=2, Kc=2592, iters=6 (5 steps).
#define KC 2592
#define HW 4096

// workspace layout (float offsets), total ~10.8 MB
#define OFF_L   0u
#define OFF_S   8192u
#define OFF_MT  16384u     // Mt[64][8192]  (M transposed: Mt[r][p])
#define OFF_NTT 540672u    // NtT[64][2592] (N row-major: N[r][col])
#define OFF_NT  706560u    // Nt[2592][64]  (N col-major: Nt[col][r])
#define OFF_T1T 872448u    // T1t[64][8192]; ALIASED as Rpart[64][8192] (disjoint lifetimes)
#define OFF_T2P 1396736u   // T2part[8][2592][64]
#define OFF_CMP 2723840u   // CmPart[21][4096]
#define OFF_CN  2809856u   // Cn[4096]
#define OFF_CMI 2813952u   // CmInv[4096]
#define OFF_CNI 2818048u   // CnInv[4096]

__global__ __launch_bounds__(256) void k_init(const float* __restrict__ inp, const float* __restrict__ s0,
                                              float* __restrict__ L, float* __restrict__ S,
                                              float* __restrict__ Mt, float* __restrict__ Nt,
                                              float* __restrict__ NtT){
  int t = blockIdx.x * 256 + threadIdx.x;
  if (t < 8192){ L[t] = inp[t]; S[t] = s0[t]; }
  if (t < 524288){ int r = t >> 13; int p = t & 8191; Mt[t] = (p == r) ? 1.0f : 0.0f; }
  if (t < 165888){ int col = t >> 6; int r = t & 63; float v = (col == r) ? 1.0f : 0.0f;
                   Nt[t] = v; NtT[r * KC + col] = v; }
}

// Rpart[r][p] = sum_{kk,ii,jj} Mt[r][(c+kk)%2][(h+ii)%64][(w+jj)%64] * N[r][kk*1296+jj*36+ii]
__global__ __launch_bounds__(128) void k_conv_R(const float* __restrict__ Mtg,
                                                const float* __restrict__ NtT,
                                                float* __restrict__ Rpart){
  __shared__ float img[128 * 65];
  __shared__ float filt[KC];
  int r = blockIdx.x, oct = blockIdx.y, tid = threadIdx.x;
  const float* gi = Mtg + (size_t)r * 8192;
  const float* gf = NtT + (size_t)r * KC;
  for (int t = tid; t < 8192; t += 128) img[(t >> 6) * 65 + (t & 63)] = gi[t];
  for (int t = tid; t < KC; t += 128) filt[t] = gf[t];
  __syncthreads();
  int c0 = tid >> 6, hloc = (tid >> 3) & 7, w0 = (tid & 7) * 8;
  int h = oct * 8 + hloc;
  float acc[8] = {0,0,0,0,0,0,0,0};
  for (int kk = 0; kk < 2; kk++){
    int crow = ((c0 + kk) & 1) << 6;
    for (int ii = 0; ii < 36; ii++){
      int base = (crow + ((h + ii) & 63)) * 65;
      int fb = kk * 1296 + ii;
      float v[16];
      #pragma unroll
      for (int s = 0; s < 16; s++) v[s] = img[base + ((w0 + s) & 63)];
      #pragma unroll
      for (int jj = 0; jj < 36; jj++){
        float f = filt[fb + jj * 36];
        #pragma unroll
        for (int t = 0; t < 8; t++) acc[t] = fmaf(f, v[(jj + t) & 15], acc[t]);
        v[jj & 15] = img[base + ((w0 + jj + 16) & 63)];
      }
    }
  }
  size_t ob = (size_t)r * 8192 + (size_t)(c0 * HW + h * 64 + w0);
  #pragma unroll
  for (int t = 0; t < 8; t++) Rpart[ob + t] = acc[t];
}

// T1t[r][p] = sum_{kk,ii,jj} L[(c-kk)%2][(h-ii)%64][(w-jj)%64] * N[r][kk*1296+jj*36+ii]
__global__ __launch_bounds__(128) void k_conv_T1(const float* __restrict__ Lg,
                                                 const float* __restrict__ NtT,
                                                 float* __restrict__ T1t){
  __shared__ float img[128 * 65];
  __shared__ float filt[KC];
  int r = blockIdx.x, oct = blockIdx.y, tid = threadIdx.x;
  const float* gf = NtT + (size_t)r * KC;
  for (int t = tid; t < 8192; t += 128) img[(t >> 6) * 65 + (t & 63)] = Lg[t];
  for (int t = tid; t < KC; t += 128) filt[t] = gf[t];
  __syncthreads();
  int c0 = tid >> 6, hloc = (tid >> 3) & 7, w0 = (tid & 7) * 8;
  int h = oct * 8 + hloc;
  float acc[8] = {0,0,0,0,0,0,0,0};
  for (int kk = 0; kk < 2; kk++){
    int crow = ((c0 - kk + 2) & 1) << 6;
    for (int ii = 0; ii < 36; ii++){
      int base = (crow + ((h - ii + 64) & 63)) * 65;
      int fb = kk * 1296 + ii;
      float v[16];
      #pragma unroll
      for (int s = 0; s < 16; s++){
        int off = (s < 8) ? s : (s - 16);
        v[s] = img[base + ((w0 + off + 64) & 63)];
      }
      #pragma unroll
      for (int jj = 0; jj < 36; jj++){
        float f = filt[fb + jj * 36];
        #pragma unroll
        for (int t = 0; t < 8; t++) acc[t] = fmaf(f, v[(t - jj) & 15], acc[t]);
        v[(7 - jj) & 15] = img[base + ((w0 - jj - 9 + 128) & 63)];
      }
    }
  }
  size_t ob = (size_t)r * 8192 + (size_t)(c0 * HW + h * 64 + w0);
  #pragma unroll
  for (int t = 0; t < 8; t++) T1t[ob + t] = acc[t];
}

// L[p] = clip((inp - S + g*R)/(g+1)); S = (inp - L)/(b+1); R = (1/Kc) * sum_r Rpart[r][p]
__global__ __launch_bounds__(256) void k_reduce_LS(const float* __restrict__ Rpart,
                                                   const float* __restrict__ inp,
                                                   const float* __restrict__ pg, const float* __restrict__ pb,
                                                   float* __restrict__ S, float* __restrict__ Ldst){
  int p = blockIdx.x * 256 + threadIdx.x;
  float acc = 0.0f;
  for (int r = 0; r < 64; r++) acc += Rpart[(size_t)r * 8192 + p];
  float R = acc * (1.0f / 2592.0f);
  float g = pg[0], b = pb[0];
  float Ln = (inp[p] - S[p] + g * R) / (g + 1.0f);
  Ln = fminf(fmaxf(Ln, 0.0f), 1.0f);
  S[p] = (inp[p] - Ln) / (b + 1.0f);
  Ldst[p] = Ln;
}

// CmPart[wg] += partial of N@N^T over a 128-col chunk (raw, unscaled)
__global__ __launch_bounds__(256) void k_cm_part(const float* __restrict__ Nt, float* __restrict__ CmPart){
  __shared__ float Nl[128 * 64];
  int cw = blockIdx.x, tid = threadIdx.x;
  int colbase = cw * 128;
  for (int t = tid; t < 8192; t += 256){
    int col = colbase + (t >> 6);
    Nl[t] = (col < KC) ? Nt[(size_t)colbase * 64 + t] : 0.0f;
  }
  __syncthreads();
  int ty = tid >> 4, tx = tid & 15;
  float acc[4][4] = {{0}};
  for (int cc = 0; cc < 128; cc++){
    float a0 = Nl[cc * 64 + ty * 4 + 0], a1 = Nl[cc * 64 + ty * 4 + 1];
    float a2 = Nl[cc * 64 + ty * 4 + 2], a3 = Nl[cc * 64 + ty * 4 + 3];
    float b0 = Nl[cc * 64 + tx * 4 + 0], b1 = Nl[cc * 64 + tx * 4 + 1];
    float b2 = Nl[cc * 64 + tx * 4 + 2], b3 = Nl[cc * 64 + tx * 4 + 3];
    acc[0][0] = fmaf(a0, b0, acc[0][0]); acc[0][1] = fmaf(a0, b1, acc[0][1]);
    acc[0][2] = fmaf(a0, b2, acc[0][2]); acc[0][3] = fmaf(a0, b3, acc[0][3]);
    acc[1][0] = fmaf(a1, b0, acc[1][0]); acc[1][1] = fmaf(a1, b1, acc[1][1]);
    acc[1][2] = fmaf(a1, b2, acc[1][2]); acc[1][3] = fmaf(a1, b3, acc[1][3]);
    acc[2][0] = fmaf(a2, b0, acc[2][0]); acc[2][1] = fmaf(a2, b1, acc[2][1]);
    acc[2][2] = fmaf(a2, b2, acc[2][2]); acc[2][3] = fmaf(a2, b3, acc[2][3]);
    acc[3][0] = fmaf(a3, b0, acc[3][0]); acc[3][1] = fmaf(a3, b1, acc[3][1]);
    acc[3][2] = fmaf(a3, b2, acc[3][2]); acc[3][3] = fmaf(a3, b3, acc[3][3]);
  }
  #pragma unroll
  for (int i = 0; i < 4; i++)
    #pragma unroll
    for (int j = 0; j < 4; j++)
      CmPart[(size_t)cw * 4096 + (ty * 4 + i) * 64 + (tx * 4 + j)] = acc[i][j];
}

// Cn_raw[r1][r2] = sum_p Mt[r1][p]*Mt[r2][p]
__global__ __launch_bounds__(64) void k_cn(const float* __restrict__ Mt, float* __restrict__ Cn){
  int e = blockIdx.x; int r1 = e >> 6, r2 = e & 63;
  if (r2 < r1) return;
  int lane = threadIdx.x;
  const float* m1 = Mt + (size_t)r1 * 8192;
  const float* m2 = Mt + (size_t)r2 * 8192;
  float acc = 0.0f;
  for (int p = lane; p < 8192; p += 64) acc = fmaf(m1[p], m2[p], acc);
  for (int off = 32; off; off >>= 1) acc += __shfl_down(acc, off, 64);
  if (lane == 0){ Cn[r1 * 64 + r2] = acc; Cn[r2 * 64 + r1] = acc; }
}

// dst = inv( 2*g*sum_w src[w] + a*I ) via Gauss-Jordan (SPD, no pivoting), single workgroup
__global__ __launch_bounds__(256) void k_inv(const float* __restrict__ src, int nparts,
                                             const float* __restrict__ pg, const float* __restrict__ pa,
                                             float* __restrict__ dst){
  __shared__ float aug[64 * 130];
  __shared__ float rowbuf[128];
  __shared__ float fcol[64];
  int tid = threadIdx.x;
  float scale = 2.0f * pg[0];
  float ad = pa[0];
  for (int t = tid; t < 4096; t += 256){
    int i = t >> 6, j = t & 63;
    float s = 0.0f;
    for (int w = 0; w < nparts; w++) s += src[(size_t)w * 4096 + t];
    aug[i * 130 + j] = scale * s + ((i == j) ? ad : 0.0f);
    aug[i * 130 + 64 + j] = (i == j) ? 1.0f : 0.0f;
  }
  __syncthreads();
  for (int j = 0; j < 64; j++){
    if (tid < 128) rowbuf[tid] = aug[j * 130 + tid];
    else if (tid < 192) fcol[tid - 128] = aug[(tid - 128) * 130 + j];
    __syncthreads();
    float pivinv = 1.0f / rowbuf[j];
    for (int e = tid; e < 8192; e += 256){
      int i = e >> 7, c = e & 127;
      float rj = rowbuf[c] * pivinv;
      float val = aug[i * 130 + c];
      aug[i * 130 + c] = (i == j) ? rj : fmaf(-fcol[i], rj, val);
    }
    __syncthreads();
  }
  for (int t = tid; t < 4096; t += 256){
    int i = t >> 6, j = t & 63;
    dst[t] = aug[i * 130 + 64 + j];
  }
}

// Mt_new[s][p] = 2g * sum_r T1t[r][p] * CmInv[r][s]
__global__ __launch_bounds__(256) void k_mn(const float* __restrict__ T1t, const float* __restrict__ CmInv,
                                            const float* __restrict__ pg, float* __restrict__ Mt){
  __shared__ float ci[4096];
  int tid = threadIdx.x;
  for (int t = tid; t < 4096; t += 256) ci[t] = CmInv[t];
  __syncthreads();
  int p = blockIdx.x * 256 + tid;
  float g2 = 2.0f * pg[0];
  float acc[64];
  #pragma unroll
  for (int s = 0; s < 64; s++) acc[s] = 0.0f;
  for (int r = 0; r < 64; r++){
    float v = T1t[(size_t)r * 8192 + p];
    #pragma unroll
    for (int s = 0; s < 64; s++) acc[s] = fmaf(v, ci[r * 64 + s], acc[s]);
  }
  #pragma unroll
  for (int s = 0; s < 64; s++) Mt[(size_t)s * 8192 + p] = g2 * acc[s];
}

// T2part[hc][col][r] = sum_{c, h in hc-chunk, w} L[c][h][w] * Mt[r][(c+kk)%2][(h+ii)%64][(w+jj)%64]
__global__ __launch_bounds__(256) void k_conv_T2(const float* __restrict__ Lg,
                                                 const float* __restrict__ Mtg,
                                                 float* __restrict__ T2part){
  __shared__ float Mi[128 * 65];
  int r = blockIdx.x, hc = blockIdx.y, tid = threadIdx.x;
  const float* gm = Mtg + (size_t)r * 8192;
  for (int t = tid; t < 8192; t += 256) Mi[(t >> 6) * 65 + (t & 63)] = gm[t];
  __syncthreads();
  if (tid >= 216) return;
  int kk = tid / 108, rest = tid % 108, ii = rest / 3, jj0 = (rest % 3) * 12;
  float acc[12];
  #pragma unroll
  for (int u = 0; u < 12; u++) acc[u] = 0.0f;
  for (int c = 0; c < 2; c++){
    for (int hl = 0; hl < 8; hl++){
      int h = hc * 8 + hl;
      int mbase = (((c + kk) & 1) * 64 + ((h + ii) & 63)) * 65;
      int lbase = (c * 64 + h) * 64;
      float v[16];
      #pragma unroll
      for (int u = 0; u < 16; u++) v[u] = Mi[mbase + ((jj0 + u) & 63)];
      #pragma unroll 16
      for (int w = 0; w < 64; w++){
        float Lv = Lg[lbase + w];   // wave-uniform -> scalar load
        #pragma unroll
        for (int u = 0; u < 12; u++) acc[u] = fmaf(Lv, v[(w + u) & 15], acc[u]);
        v[w & 15] = Mi[mbase + ((w + jj0 + 16) & 63)];
      }
    }
  }
  #pragma unroll
  for (int u = 0; u < 12; u++){
    int col = kk * 1296 + (jj0 + u) * 36 + ii;
    T2part[((size_t)hc * KC + col) * 64 + r] = acc[u];
  }
}

// Nt_new[col][r] = 2g * sum_s CnInv[r][s] * T2[s][col];  T2[s][col] = sum_hc T2part[hc][col][s]
__global__ __launch_bounds__(256) void k_nn(const float* __restrict__ T2part, const float* __restrict__ CnInv,
                                            const float* __restrict__ pg,
                                            float* __restrict__ Nt, float* __restrict__ NtT){
  __shared__ float ci[4096];
  int tid = threadIdx.x;
  for (int t = tid; t < 4096; t += 256) ci[t] = CnInv[t];
  __syncthreads();
  int col = blockIdx.x * 256 + tid;
  if (col >= KC) return;
  float g2 = 2.0f * pg[0];
  float acc[64];
  #pragma unroll
  for (int rr = 0; rr < 64; rr++) acc[rr] = 0.0f;
  for (int s = 0; s < 64; s++){
    float tv = 0.0f;
    #pragma unroll
    for (int w = 0; w < 8; w++) tv += T2part[((size_t)w * KC + col) * 64 + s];
    #pragma unroll
    for (int rr = 0; rr < 64; rr++) acc[rr] = fmaf(tv, ci[s * 64 + rr], acc[rr]);  // CnInv symmetric
  }
  #pragma unroll
  for (int rr = 0; rr < 64; rr++){
    float v = g2 * acc[rr];
    Nt[(size_t)col * 64 + rr] = v;
    NtT[(size_t)rr * KC + col] = v;
  }
}

extern "C" void kernel_launch(void* const* d_in, const int* in_sizes, int n_in,
                              void* d_out, int out_size, void* d_ws, size_t ws_size,
                              hipStream_t stream) {
  const float* inp = (const float*)d_in[0];
  const float* s0  = (const float*)d_in[1];
  const float* pa  = (const float*)d_in[2];
  const float* pb  = (const float*)d_in[3];
  const float* pg  = (const float*)d_in[4];
  // d_in[5] = iters (fixed 6 -> 5 scan steps; only final L is needed, so step 5 is partial)
  float* ws  = (float*)d_ws;
  float* L   = ws + OFF_L;  float* S   = ws + OFF_S;   float* Mt  = ws + OFF_MT;
  float* NtT = ws + OFF_NTT; float* Nt = ws + OFF_NT;  float* T1t = ws + OFF_T1T;
  float* Rp  = ws + OFF_T1T; // aliased: disjoint lifetime with T1t
  float* T2p = ws + OFF_T2P; float* CmP = ws + OFF_CMP; float* Cn = ws + OFF_CN;
  float* CmI = ws + OFF_CMI; float* CnI = ws + OFF_CNI;
  float* out = (float*)d_out;

  k_init<<<2048, 256, 0, stream>>>(inp, s0, L, S, Mt, Nt, NtT);
  for (int step = 0; step < 5; step++){
    k_conv_R<<<dim3(64, 8), 128, 0, stream>>>(Mt, NtT, Rp);
    bool last = (step == 4);
    k_reduce_LS<<<32, 256, 0, stream>>>(Rp, inp, pg, pb, S, last ? out : L);
    if (last) break;
    k_cm_part<<<21, 256, 0, stream>>>(Nt, CmP);
    k_inv<<<1, 256, 0, stream>>>(CmP, 21, pg, pa, CmI);
    k_conv_T1<<<dim3(64, 8), 128, 0, stream>>>(L, NtT, T1t);
    k_mn<<<32, 256, 0, stream>>>(T1t, CmI, pg, Mt);
    k_cn<<<4096, 64, 0, stream>>>(Mt, Cn);
    k_inv<<<1, 256, 0, stream>>>(Cn, 1, pg, pa, CnI);
    k_conv_T2<<<dim3(64, 8), 256, 0, stream>>>(L, Mt, T2p);
    k_nn<<<11, 256, 0, stream>>>(T2p, CnI, pg, Nt, NtT);
  }
}

// Round 2
// 2070.689 us; speedup vs baseline: 1.5980x; 1.5980x over previous
//
#include <hip/hip_runtime.h>

// Problem constants: B=1, C=2, H=W=64, m=8192, mk=64, K1=K2=36, K3=2, Kc=2592, iters=6 (5 steps).
#define KC 2592
#define HW 4096

// workspace layout (float offsets), total ~10.8 MB
#define OFF_L   0u
#define OFF_S   8192u
#define OFF_MT  16384u     // Mt[64][8192]  (M transposed: Mt[r][p])
#define OFF_NTT 540672u    // NtT[64][2592] (N row-major: N[r][col])
#define OFF_NT  706560u    // Nt[2592][64]  (N col-major: Nt[col][r])
#define OFF_T1T 872448u    // T1t[64][8192]; ALIASED as Rpart[64][8192] (disjoint lifetimes)
#define OFF_T2P 1396736u   // T2part[8][2592][64]
#define OFF_CMP 2723840u   // CmPart[21][4096]
#define OFF_CN  2809856u   // Cn[4096]
#define OFF_CMI 2813952u   // CmInv[4096]
#define OFF_CNI 2818048u   // CnInv[4096]

__global__ __launch_bounds__(256) void k_init(const float* __restrict__ inp, const float* __restrict__ s0,
                                              float* __restrict__ L, float* __restrict__ S,
                                              float* __restrict__ Mt, float* __restrict__ Nt,
                                              float* __restrict__ NtT){
  int t = blockIdx.x * 256 + threadIdx.x;
  if (t < 8192){ L[t] = inp[t]; S[t] = s0[t]; }
  if (t < 524288){ int r = t >> 13; int p = t & 8191; Mt[t] = (p == r) ? 1.0f : 0.0f; }
  if (t < 165888){ int col = t >> 6; int r = t & 63; float v = (col == r) ? 1.0f : 0.0f;
                   Nt[t] = v; NtT[r * KC + col] = v; }
}

// Rpart[r][p] = sum_{kk,ii,jj} Mt[r][(c+kk)%2][(h+ii)%64][(w+jj)%64] * N[r][kk*1296+jj*36+ii]
__global__ __launch_bounds__(128) void k_conv_R(const float* __restrict__ Mtg,
                                                const float* __restrict__ NtT,
                                                float* __restrict__ Rpart){
  __shared__ float img[128 * 65];
  __shared__ float filt[KC];
  int r = blockIdx.x, oct = blockIdx.y, tid = threadIdx.x;
  const float* gi = Mtg + (size_t)r * 8192;
  const float* gf = NtT + (size_t)r * KC;
  for (int t = tid; t < 8192; t += 128) img[(t >> 6) * 65 + (t & 63)] = gi[t];
  for (int t = tid; t < KC; t += 128) filt[t] = gf[t];
  __syncthreads();
  int c0 = tid >> 6, hloc = (tid >> 3) & 7, w0 = (tid & 7) * 8;
  int h = oct * 8 + hloc;
  float acc[8] = {0,0,0,0,0,0,0,0};
  for (int kk = 0; kk < 2; kk++){
    int crow = ((c0 + kk) & 1) << 6;
    for (int ii = 0; ii < 36; ii++){
      int base = (crow + ((h + ii) & 63)) * 65;
      int fb = kk * 1296 + ii;
      float v[16];
      #pragma unroll
      for (int s = 0; s < 16; s++) v[s] = img[base + ((w0 + s) & 63)];
      #pragma unroll
      for (int jj = 0; jj < 36; jj++){
        float f = filt[fb + jj * 36];
        #pragma unroll
        for (int t = 0; t < 8; t++) acc[t] = fmaf(f, v[(jj + t) & 15], acc[t]);
        v[jj & 15] = img[base + ((w0 + jj + 16) & 63)];
      }
    }
  }
  size_t ob = (size_t)r * 8192 + (size_t)(c0 * HW + h * 64 + w0);
  #pragma unroll
  for (int t = 0; t < 8; t++) Rpart[ob + t] = acc[t];
}

// T1t[r][p] = sum_{kk,ii,jj} L[(c-kk)%2][(h-ii)%64][(w-jj)%64] * N[r][kk*1296+jj*36+ii]
__global__ __launch_bounds__(128) void k_conv_T1(const float* __restrict__ Lg,
                                                 const float* __restrict__ NtT,
                                                 float* __restrict__ T1t){
  __shared__ float img[128 * 65];
  __shared__ float filt[KC];
  int r = blockIdx.x, oct = blockIdx.y, tid = threadIdx.x;
  const float* gf = NtT + (size_t)r * KC;
  for (int t = tid; t < 8192; t += 128) img[(t >> 6) * 65 + (t & 63)] = Lg[t];
  for (int t = tid; t < KC; t += 128) filt[t] = gf[t];
  __syncthreads();
  int c0 = tid >> 6, hloc = (tid >> 3) & 7, w0 = (tid & 7) * 8;
  int h = oct * 8 + hloc;
  float acc[8] = {0,0,0,0,0,0,0,0};
  for (int kk = 0; kk < 2; kk++){
    int crow = ((c0 - kk + 2) & 1) << 6;
    for (int ii = 0; ii < 36; ii++){
      int base = (crow + ((h - ii + 64) & 63)) * 65;
      int fb = kk * 1296 + ii;
      float v[16];
      #pragma unroll
      for (int s = 0; s < 16; s++){
        int off = (s < 8) ? s : (s - 16);
        v[s] = img[base + ((w0 + off + 64) & 63)];
      }
      #pragma unroll
      for (int jj = 0; jj < 36; jj++){
        float f = filt[fb + jj * 36];
        #pragma unroll
        for (int t = 0; t < 8; t++) acc[t] = fmaf(f, v[(t - jj) & 15], acc[t]);
        v[(7 - jj) & 15] = img[base + ((w0 - jj - 9 + 128) & 63)];
      }
    }
  }
  size_t ob = (size_t)r * 8192 + (size_t)(c0 * HW + h * 64 + w0);
  #pragma unroll
  for (int t = 0; t < 8; t++) T1t[ob + t] = acc[t];
}

// L[p] = clip((inp - S + g*R)/(g+1)); S = (inp - L)/(b+1); R = (1/Kc) * sum_r Rpart[r][p]
__global__ __launch_bounds__(256) void k_reduce_LS(const float* __restrict__ Rpart,
                                                   const float* __restrict__ inp,
                                                   const float* __restrict__ pg, const float* __restrict__ pb,
                                                   float* __restrict__ S, float* __restrict__ Ldst){
  int p = blockIdx.x * 256 + threadIdx.x;
  float acc = 0.0f;
  for (int r = 0; r < 64; r++) acc += Rpart[(size_t)r * 8192 + p];
  float R = acc * (1.0f / 2592.0f);
  float g = pg[0], b = pb[0];
  float Ln = (inp[p] - S[p] + g * R) / (g + 1.0f);
  Ln = fminf(fmaxf(Ln, 0.0f), 1.0f);
  S[p] = (inp[p] - Ln) / (b + 1.0f);
  Ldst[p] = Ln;
}

// CmPart[wg] += partial of N@N^T over a 128-col chunk (raw, unscaled)
__global__ __launch_bounds__(256) void k_cm_part(const float* __restrict__ Nt, float* __restrict__ CmPart){
  __shared__ float Nl[128 * 64];
  int cw = blockIdx.x, tid = threadIdx.x;
  int colbase = cw * 128;
  for (int t = tid; t < 8192; t += 256){
    int col = colbase + (t >> 6);
    Nl[t] = (col < KC) ? Nt[(size_t)colbase * 64 + t] : 0.0f;
  }
  __syncthreads();
  int ty = tid >> 4, tx = tid & 15;
  float acc[4][4] = {{0}};
  for (int cc = 0; cc < 128; cc++){
    float a0 = Nl[cc * 64 + ty * 4 + 0], a1 = Nl[cc * 64 + ty * 4 + 1];
    float a2 = Nl[cc * 64 + ty * 4 + 2], a3 = Nl[cc * 64 + ty * 4 + 3];
    float b0 = Nl[cc * 64 + tx * 4 + 0], b1 = Nl[cc * 64 + tx * 4 + 1];
    float b2 = Nl[cc * 64 + tx * 4 + 2], b3 = Nl[cc * 64 + tx * 4 + 3];
    acc[0][0] = fmaf(a0, b0, acc[0][0]); acc[0][1] = fmaf(a0, b1, acc[0][1]);
    acc[0][2] = fmaf(a0, b2, acc[0][2]); acc[0][3] = fmaf(a0, b3, acc[0][3]);
    acc[1][0] = fmaf(a1, b0, acc[1][0]); acc[1][1] = fmaf(a1, b1, acc[1][1]);
    acc[1][2] = fmaf(a1, b2, acc[1][2]); acc[1][3] = fmaf(a1, b3, acc[1][3]);
    acc[2][0] = fmaf(a2, b0, acc[2][0]); acc[2][1] = fmaf(a2, b1, acc[2][1]);
    acc[2][2] = fmaf(a2, b2, acc[2][2]); acc[2][3] = fmaf(a2, b3, acc[2][3]);
    acc[3][0] = fmaf(a3, b0, acc[3][0]); acc[3][1] = fmaf(a3, b1, acc[3][1]);
    acc[3][2] = fmaf(a3, b2, acc[3][2]); acc[3][3] = fmaf(a3, b3, acc[3][3]);
  }
  #pragma unroll
  for (int i = 0; i < 4; i++)
    #pragma unroll
    for (int j = 0; j < 4; j++)
      CmPart[(size_t)cw * 4096 + (ty * 4 + i) * 64 + (tx * 4 + j)] = acc[i][j];
}

// Cn_raw[r1][r2] = sum_p Mt[r1][p]*Mt[r2][p]
__global__ __launch_bounds__(64) void k_cn(const float* __restrict__ Mt, float* __restrict__ Cn){
  int e = blockIdx.x; int r1 = e >> 6, r2 = e & 63;
  if (r2 < r1) return;
  int lane = threadIdx.x;
  const float* m1 = Mt + (size_t)r1 * 8192;
  const float* m2 = Mt + (size_t)r2 * 8192;
  float acc = 0.0f;
  for (int p = lane; p < 8192; p += 64) acc = fmaf(m1[p], m2[p], acc);
  for (int off = 32; off; off >>= 1) acc += __shfl_down(acc, off, 64);
  if (lane == 0){ Cn[r1 * 64 + r2] = acc; Cn[r2 * 64 + r1] = acc; }
}

// dst = inv( 2*g*sum_w src[w] + a*I ) via register-resident Gauss-Jordan (SPD, no pivoting).
// Thread tid owns row i=tid>>2, cols c=(tid&3)+4k (k=0..31) of the 64x128 augmented matrix.
// Per pivot only row j (128 f) and col j (64 f) go through LDS; 32 indep ds_reads + 32 fma
// per thread pipeline the LDS latency that made the previous version 249 us.
__global__ __launch_bounds__(256) void k_inv(const float* __restrict__ src, int nparts,
                                             const float* __restrict__ pg, const float* __restrict__ pa,
                                             float* __restrict__ dst){
  __shared__ float rowbuf[128];
  __shared__ float fcol[64];
  int tid = threadIdx.x;
  int i = tid >> 2, c4 = tid & 3;
  float scale = 2.0f * pg[0];
  float ad = pa[0];
  float a[32];
  #pragma unroll
  for (int k = 0; k < 16; k++){           // A-part columns (c4+4k < 64)
    int col = c4 + 4 * k;
    float s = 0.0f;
    for (int w = 0; w < nparts; w++) s += src[(size_t)w * 4096 + i * 64 + col];
    a[k] = scale * s + ((i == col) ? ad : 0.0f);
  }
  #pragma unroll
  for (int k = 16; k < 32; k++){          // identity columns
    int col = c4 + 4 * k - 64;
    a[k] = (i == col) ? 1.0f : 0.0f;
  }
  #pragma unroll
  for (int j = 0; j < 64; j++){
    if (c4 == (j & 3)) fcol[i] = a[j >> 2];       // old column j (j literal -> static reg idx)
    if (i == j){
      #pragma unroll
      for (int k = 0; k < 32; k++) rowbuf[c4 + 4 * k] = a[k];  // old row j
    }
    __syncthreads();
    float fj = fcol[i];
    float pivinv = 1.0f / fcol[j];
    float t = fj * pivinv;
    #pragma unroll
    for (int k = 0; k < 32; k++){
      float rv = rowbuf[c4 + 4 * k];
      a[k] = (i == j) ? (rv * pivinv) : fmaf(-t, rv, a[k]);
    }
    __syncthreads();
  }
  #pragma unroll
  for (int k = 16; k < 32; k++){
    int col = c4 + 4 * k - 64;
    dst[i * 64 + col] = a[k];
  }
}

// Mt_new[s][p] = 2g * sum_r T1t[r][p] * CmInv[r][s]
__global__ __launch_bounds__(256) void k_mn(const float* __restrict__ T1t, const float* __restrict__ CmInv,
                                            const float* __restrict__ pg, float* __restrict__ Mt){
  __shared__ float ci[4096];
  int tid = threadIdx.x;
  for (int t = tid; t < 4096; t += 256) ci[t] = CmInv[t];
  __syncthreads();
  int p = blockIdx.x * 256 + tid;
  float g2 = 2.0f * pg[0];
  float acc[64];
  #pragma unroll
  for (int s = 0; s < 64; s++) acc[s] = 0.0f;
  for (int r = 0; r < 64; r++){
    float v = T1t[(size_t)r * 8192 + p];
    #pragma unroll
    for (int s = 0; s < 64; s++) acc[s] = fmaf(v, ci[r * 64 + s], acc[s]);
  }
  #pragma unroll
  for (int s = 0; s < 64; s++) Mt[(size_t)s * 8192 + p] = g2 * acc[s];
}

// T2part[hc][col][r] = sum_{c, h in hc-chunk, w} L[c][h][w] * Mt[r][(c+kk)%2][(h+ii)%64][(w+jj)%64]
__global__ __launch_bounds__(256) void k_conv_T2(const float* __restrict__ Lg,
                                                 const float* __restrict__ Mtg,
                                                 float* __restrict__ T2part){
  __shared__ float Mi[128 * 65];
  int r = blockIdx.x, hc = blockIdx.y, tid = threadIdx.x;
  const float* gm = Mtg + (size_t)r * 8192;
  for (int t = tid; t < 8192; t += 256) Mi[(t >> 6) * 65 + (t & 63)] = gm[t];
  __syncthreads();
  if (tid >= 216) return;
  int kk = tid / 108, rest = tid % 108, ii = rest / 3, jj0 = (rest % 3) * 12;
  float acc[12];
  #pragma unroll
  for (int u = 0; u < 12; u++) acc[u] = 0.0f;
  for (int c = 0; c < 2; c++){
    for (int hl = 0; hl < 8; hl++){
      int h = hc * 8 + hl;
      int mbase = (((c + kk) & 1) * 64 + ((h + ii) & 63)) * 65;
      int lbase = (c * 64 + h) * 64;
      float v[16];
      #pragma unroll
      for (int u = 0; u < 16; u++) v[u] = Mi[mbase + ((jj0 + u) & 63)];
      #pragma unroll 16
      for (int w = 0; w < 64; w++){
        float Lv = Lg[lbase + w];   // wave-uniform -> scalar load
        #pragma unroll
        for (int u = 0; u < 12; u++) acc[u] = fmaf(Lv, v[(w + u) & 15], acc[u]);
        v[w & 15] = Mi[mbase + ((w + jj0 + 16) & 63)];
      }
    }
  }
  #pragma unroll
  for (int u = 0; u < 12; u++){
    int col = kk * 1296 + (jj0 + u) * 36 + ii;
    T2part[((size_t)hc * KC + col) * 64 + r] = acc[u];
  }
}

// Nt_new[col][r] = 2g * sum_s CnInv[r][s] * T2[s][col];  T2[s][col] = sum_hc T2part[hc][col][s]
__global__ __launch_bounds__(256) void k_nn(const float* __restrict__ T2part, const float* __restrict__ CnInv,
                                            const float* __restrict__ pg,
                                            float* __restrict__ Nt, float* __restrict__ NtT){
  __shared__ float ci[4096];
  int tid = threadIdx.x;
  for (int t = tid; t < 4096; t += 256) ci[t] = CnInv[t];
  __syncthreads();
  int col = blockIdx.x * 256 + tid;
  if (col >= KC) return;
  float g2 = 2.0f * pg[0];
  float acc[64];
  #pragma unroll
  for (int rr = 0; rr < 64; rr++) acc[rr] = 0.0f;
  for (int s = 0; s < 64; s++){
    float tv = 0.0f;
    #pragma unroll
    for (int w = 0; w < 8; w++) tv += T2part[((size_t)w * KC + col) * 64 + s];
    #pragma unroll
    for (int rr = 0; rr < 64; rr++) acc[rr] = fmaf(tv, ci[s * 64 + rr], acc[rr]);  // CnInv symmetric
  }
  #pragma unroll
  for (int rr = 0; rr < 64; rr++){
    float v = g2 * acc[rr];
    Nt[(size_t)col * 64 + rr] = v;
    NtT[(size_t)rr * KC + col] = v;
  }
}

extern "C" void kernel_launch(void* const* d_in, const int* in_sizes, int n_in,
                              void* d_out, int out_size, void* d_ws, size_t ws_size,
                              hipStream_t stream) {
  const float* inp = (const float*)d_in[0];
  const float* s0  = (const float*)d_in[1];
  const float* pa  = (const float*)d_in[2];
  const float* pb  = (const float*)d_in[3];
  const float* pg  = (const float*)d_in[4];
  // d_in[5] = iters (fixed 6 -> 5 scan steps; only final L is needed, so step 5 is partial)
  float* ws  = (float*)d_ws;
  float* L   = ws + OFF_L;  float* S   = ws + OFF_S;   float* Mt  = ws + OFF_MT;
  float* NtT = ws + OFF_NTT; float* Nt = ws + OFF_NT;  float* T1t = ws + OFF_T1T;
  float* Rp  = ws + OFF_T1T; // aliased: disjoint lifetime with T1t
  float* T2p = ws + OFF_T2P; float* CmP = ws + OFF_CMP; float* Cn = ws + OFF_CN;
  float* CmI = ws + OFF_CMI; float* CnI = ws + OFF_CNI;
  float* out = (float*)d_out;

  k_init<<<2048, 256, 0, stream>>>(inp, s0, L, S, Mt, Nt, NtT);
  for (int step = 0; step < 5; step++){
    k_conv_R<<<dim3(64, 8), 128, 0, stream>>>(Mt, NtT, Rp);
    bool last = (step == 4);
    k_reduce_LS<<<32, 256, 0, stream>>>(Rp, inp, pg, pb, S, last ? out : L);
    if (last) break;
    k_cm_part<<<21, 256, 0, stream>>>(Nt, CmP);
    k_inv<<<1, 256, 0, stream>>>(CmP, 21, pg, pa, CmI);
    k_conv_T1<<<dim3(64, 8), 128, 0, stream>>>(L, NtT, T1t);
    k_mn<<<32, 256, 0, stream>>>(T1t, CmI, pg, Mt);
    k_cn<<<4096, 64, 0, stream>>>(Mt, Cn);
    k_inv<<<1, 256, 0, stream>>>(Cn, 1, pg, pa, CnI);
    k_conv_T2<<<dim3(64, 8), 256, 0, stream>>>(L, Mt, T2p);
    k_nn<<<11, 256, 0, stream>>>(T2p, CnI, pg, Nt, NtT);
  }
}

// Round 3
// 1310.721 us; speedup vs baseline: 2.5246x; 1.5798x over previous
//
#include <hip/hip_runtime.h>

// Problem constants: B=1, C=2, H=W=64, m=8192, mk=64, K1=K2=36, K3=2, Kc=2592, iters=6 (5 steps).
#define KC 2592
#define KCP 2624           // padded NtT row stride (zeros in tail)
#define HW 4096

// workspace layout (float offsets), total 2433024 floats = 9.73 MB (< proven 11.3 MB footprint)
#define OFF_L    0u
#define OFF_S    8192u
#define OFF_MT   16384u    // Mt[64][8192]
#define OFF_NTT  540672u   // NtT[64][2624], layout d=(kk*36+ii)*36+jj, cols 2592..2623 zero
#define OFF_BIG  708608u   // Rpart[128][8192] / T1t[128][8192] (aliased, disjoint lifetimes)
#define OFF_T2P  1757184u  // T2part[4][64][2592]  ([hc][r][col])
#define OFF_GRAM 2420736u  // raw gram 64x64 (shared by Cm and Cn phases)
#define OFF_CMI  2424832u
#define OFF_CNI  2428928u

__global__ __launch_bounds__(256) void k_init(const float* __restrict__ inp, const float* __restrict__ s0,
                                              float* __restrict__ L, float* __restrict__ S,
                                              float* __restrict__ Mt, float* __restrict__ NtT){
  int t = blockIdx.x * 256 + threadIdx.x;
  if (t < 8192){ L[t] = inp[t]; S[t] = s0[t]; }
  if (t < 524288){ int r = t >> 13; int p = t & 8191; Mt[t] = (p == r) ? 1.0f : 0.0f; }
  if (t < 167936){ int r = t / KCP; int d = t - r * KCP;
                   int dr = (r % 36) * 36 + r / 36;   // N0[r][col]=delta(col==r) -> d=(0*36+ii)*36+jj, col=jj*36+ii=r
                   NtT[t] = (d == dr) ? 1.0f : 0.0f; }
}

// ---- conv_R: Rpart[r+64z][p] = sum_{kk, ii in half z, jj} Mt[r][(c+kk)%2][(h+ii)%64][(w+jj)%64] * f[kk][ii][jj]
__global__ __launch_bounds__(128) void k_conv_R(const float* __restrict__ Mtg,
                                                const float* __restrict__ NtT,
                                                float* __restrict__ Rpart){
  __shared__ float img[128 * 68];
  __shared__ float4 filt4[324];
  int r = blockIdx.x, oct = blockIdx.y, z = blockIdx.z, tid = threadIdx.x;
  const float4* gi4 = (const float4*)(Mtg + (size_t)r * 8192);
  for (int t = tid; t < 2048; t += 128){
    float4 v4 = gi4[t];
    int row = t >> 4, cb = (t & 15) * 4;
    float* d = &img[row * 68 + cb];
    d[0] = v4.x; d[1] = v4.y; d[2] = v4.z; d[3] = v4.w;
  }
  int iilo = z * 18;
  const float* gf = NtT + (size_t)r * KCP;
  for (int t = tid; t < 324; t += 128){
    int kk = t / 162; int rem4 = t - kk * 162;
    filt4[t] = *(const float4*)(gf + kk * 1296 + iilo * 36 + rem4 * 4);
  }
  __syncthreads();
  int c0 = tid >> 6, hloc = (tid >> 3) & 7, w0 = (tid & 7) * 8;
  int h = oct * 8 + hloc;
  float acc[8] = {0,0,0,0,0,0,0,0};
  #pragma unroll 1
  for (int kk = 0; kk < 2; kk++){
    int crow = ((c0 + kk) & 1) << 6;
    #pragma unroll 1
    for (int iix = 0; iix < 18; iix++){
      int ii = iilo + iix;
      const float* ib = &img[(crow + ((h + ii) & 63)) * 68];
      float v[16];
      {
        float4 t0 = *(const float4*)&ib[w0];
        float4 t1 = *(const float4*)&ib[(w0 + 4) & 63];
        float4 t2 = *(const float4*)&ib[(w0 + 8) & 63];
        float4 t3 = *(const float4*)&ib[(w0 + 12) & 63];
        v[0]=t0.x; v[1]=t0.y; v[2]=t0.z; v[3]=t0.w;
        v[4]=t1.x; v[5]=t1.y; v[6]=t1.z; v[7]=t1.w;
        v[8]=t2.x; v[9]=t2.y; v[10]=t2.z; v[11]=t2.w;
        v[12]=t3.x; v[13]=t3.y; v[14]=t3.z; v[15]=t3.w;
      }
      const float4* fb = &filt4[(kk * 18 + iix) * 9];
      #pragma unroll
      for (int g = 0; g < 9; g++){
        float4 ff = fb[g];
        #pragma unroll
        for (int u = 0; u < 8; u++) acc[u] = fmaf(ff.x, v[(u + 4*g + 0) & 15], acc[u]);
        #pragma unroll
        for (int u = 0; u < 8; u++) acc[u] = fmaf(ff.y, v[(u + 4*g + 1) & 15], acc[u]);
        #pragma unroll
        for (int u = 0; u < 8; u++) acc[u] = fmaf(ff.z, v[(u + 4*g + 2) & 15], acc[u]);
        #pragma unroll
        for (int u = 0; u < 8; u++) acc[u] = fmaf(ff.w, v[(u + 4*g + 3) & 15], acc[u]);
        if (g < 7){
          float4 nv = *(const float4*)&ib[(w0 + 16 + 4*g) & 63];
          int s = (4*g) & 15;
          v[s] = nv.x; v[s+1] = nv.y; v[s+2] = nv.z; v[s+3] = nv.w;
        }
      }
    }
  }
  size_t ob = ((size_t)r + 64 * z) * 8192 + (size_t)(c0 * HW + h * 64 + w0);
  *(float4*)&Rpart[ob]     = make_float4(acc[0], acc[1], acc[2], acc[3]);
  *(float4*)&Rpart[ob + 4] = make_float4(acc[4], acc[5], acc[6], acc[7]);
}

// ---- conv_T1: T1t[r+64z][p] = sum L[(c-kk)%2][(h-ii)%64][(w-jj)%64] * f[kk][ii][jj]
__global__ __launch_bounds__(128) void k_conv_T1(const float* __restrict__ Lg,
                                                 const float* __restrict__ NtT,
                                                 float* __restrict__ T1t){
  __shared__ float img[128 * 68];
  __shared__ float4 filt4[324];
  int r = blockIdx.x, oct = blockIdx.y, z = blockIdx.z, tid = threadIdx.x;
  const float4* gi4 = (const float4*)Lg;
  for (int t = tid; t < 2048; t += 128){
    float4 v4 = gi4[t];
    int row = t >> 4, cb = (t & 15) * 4;
    float* d = &img[row * 68 + cb];
    d[0] = v4.x; d[1] = v4.y; d[2] = v4.z; d[3] = v4.w;
  }
  int iilo = z * 18;
  const float* gf = NtT + (size_t)r * KCP;
  for (int t = tid; t < 324; t += 128){
    int kk = t / 162; int rem4 = t - kk * 162;
    filt4[t] = *(const float4*)(gf + kk * 1296 + iilo * 36 + rem4 * 4);
  }
  __syncthreads();
  int c0 = tid >> 6, hloc = (tid >> 3) & 7, w0 = (tid & 7) * 8;
  int h = oct * 8 + hloc;
  float acc[8] = {0,0,0,0,0,0,0,0};
  #pragma unroll 1
  for (int kk = 0; kk < 2; kk++){
    int crow = ((c0 - kk + 2) & 1) << 6;
    #pragma unroll 1
    for (int iix = 0; iix < 18; iix++){
      int ii = iilo + iix;
      const float* ib = &img[(crow + ((h - ii + 64) & 63)) * 68];
      float v[16];
      {
        float4 t0 = *(const float4*)&ib[(w0 - 8 + 64) & 63];
        float4 t1 = *(const float4*)&ib[(w0 - 4 + 64) & 63];
        float4 t2 = *(const float4*)&ib[w0];
        float4 t3 = *(const float4*)&ib[(w0 + 4) & 63];
        v[8]=t0.x;  v[9]=t0.y;  v[10]=t0.z; v[11]=t0.w;
        v[12]=t1.x; v[13]=t1.y; v[14]=t1.z; v[15]=t1.w;
        v[0]=t2.x;  v[1]=t2.y;  v[2]=t2.z;  v[3]=t2.w;
        v[4]=t3.x;  v[5]=t3.y;  v[6]=t3.z;  v[7]=t3.w;
      }
      const float4* fb = &filt4[(kk * 18 + iix) * 9];
      #pragma unroll
      for (int g = 0; g < 9; g++){
        float4 ff = fb[g];
        #pragma unroll
        for (int u = 0; u < 8; u++) acc[u] = fmaf(ff.x, v[(u - (4*g + 0)) & 15], acc[u]);
        #pragma unroll
        for (int u = 0; u < 8; u++) acc[u] = fmaf(ff.y, v[(u - (4*g + 1)) & 15], acc[u]);
        #pragma unroll
        for (int u = 0; u < 8; u++) acc[u] = fmaf(ff.z, v[(u - (4*g + 2)) & 15], acc[u]);
        #pragma unroll
        for (int u = 0; u < 8; u++) acc[u] = fmaf(ff.w, v[(u - (4*g + 3)) & 15], acc[u]);
        if (g < 7){
          float4 nv = *(const float4*)&ib[(w0 - 4*g - 12 + 64) & 63];
          int s = (4 - 4*g) & 15;
          v[s] = nv.x; v[s+1] = nv.y; v[s+2] = nv.z; v[s+3] = nv.w;
        }
      }
    }
  }
  size_t ob = ((size_t)r + 64 * z) * 8192 + (size_t)(c0 * HW + h * 64 + w0);
  *(float4*)&T1t[ob]     = make_float4(acc[0], acc[1], acc[2], acc[3]);
  *(float4*)&T1t[ob + 4] = make_float4(acc[4], acc[5], acc[6], acc[7]);
}

// L[p] = clip((inp - S + g*R)/(g+1)); S = (inp - L)/(b+1); R = (1/Kc) * sum_{128 slices} Rpart
__global__ __launch_bounds__(256) void k_reduce_LS(const float* __restrict__ Rpart,
                                                   const float* __restrict__ inp,
                                                   const float* __restrict__ pg, const float* __restrict__ pb,
                                                   float* __restrict__ S, float* __restrict__ Ldst){
  int p = blockIdx.x * 256 + threadIdx.x;
  float acc = 0.0f;
  for (int r = 0; r < 128; r++) acc += Rpart[(size_t)r * 8192 + p];
  float R = acc * (1.0f / 2592.0f);
  float g = pg[0], b = pb[0];
  float Ln = (inp[p] - S[p] + g * R) / (g + 1.0f);
  Ln = fminf(fmaxf(Ln, 0.0f), 1.0f);
  S[p] = (inp[p] - Ln) / (b + 1.0f);
  Ldst[p] = Ln;
}

// raw gram: out[r1][r2] = dot(rows[r1], rows[r2]) over len4 float4s (row stride in floats)
__global__ __launch_bounds__(64) void k_gram(const float* __restrict__ rows, int stride, int len4,
                                             float* __restrict__ out){
  int e = blockIdx.x; int r1 = e >> 6, r2 = e & 63;
  if (r2 < r1) return;
  int lane = threadIdx.x;
  const float4* a = (const float4*)(rows + (size_t)r1 * stride);
  const float4* b = (const float4*)(rows + (size_t)r2 * stride);
  float acc = 0.0f;
  for (int p = lane; p < len4; p += 64){
    float4 x = a[p], y = b[p];
    acc = fmaf(x.x, y.x, acc); acc = fmaf(x.y, y.y, acc);
    acc = fmaf(x.z, y.z, acc); acc = fmaf(x.w, y.w, acc);
  }
  for (int off = 32; off; off >>= 1) acc += __shfl_down(acc, off, 64);
  if (lane == 0){ out[r1 * 64 + r2] = acc; out[r2 * 64 + r1] = acc; }
}

// dst = inv( 2*g*gram + a*I ), register-resident Gauss-Jordan (SPD, no pivoting)
__global__ __launch_bounds__(256) void k_inv(const float* __restrict__ src,
                                             const float* __restrict__ pg, const float* __restrict__ pa,
                                             float* __restrict__ dst){
  __shared__ float rowbuf[128];
  __shared__ float fcol[64];
  int tid = threadIdx.x;
  int i = tid >> 2, c4 = tid & 3;
  float scale = 2.0f * pg[0];
  float ad = pa[0];
  float a[32];
  #pragma unroll
  for (int k = 0; k < 16; k++){
    int col = c4 + 4 * k;
    a[k] = scale * src[i * 64 + col] + ((i == col) ? ad : 0.0f);
  }
  #pragma unroll
  for (int k = 16; k < 32; k++){
    int col = c4 + 4 * k - 64;
    a[k] = (i == col) ? 1.0f : 0.0f;
  }
  #pragma unroll
  for (int j = 0; j < 64; j++){
    if (c4 == (j & 3)) fcol[i] = a[j >> 2];
    if (i == j){
      #pragma unroll
      for (int k = 0; k < 32; k++) rowbuf[c4 + 4 * k] = a[k];
    }
    __syncthreads();
    float fj = fcol[i];
    float pivinv = 1.0f / fcol[j];
    float t = fj * pivinv;
    #pragma unroll
    for (int k = 0; k < 32; k++){
      float rv = rowbuf[c4 + 4 * k];
      a[k] = (i == j) ? (rv * pivinv) : fmaf(-t, rv, a[k]);
    }
    __syncthreads();
  }
  #pragma unroll
  for (int k = 16; k < 32; k++){
    int col = c4 + 4 * k - 64;
    dst[i * 64 + col] = a[k];
  }
}

// Mt_new[s][p] = 2g * sum_{r<64} (T1t[r][p]+T1t[r+64][p]) * CmInv[r][s]
__global__ __launch_bounds__(256) void k_mn(const float* __restrict__ T1t, const float* __restrict__ CmInv,
                                            const float* __restrict__ pg, float* __restrict__ Mt){
  __shared__ float4 ci4[1024];
  int tid = threadIdx.x;
  const float4* g4 = (const float4*)CmInv;
  for (int t = tid; t < 1024; t += 256) ci4[t] = g4[t];
  __syncthreads();
  int p = blockIdx.x * 256 + tid;
  float g2 = 2.0f * pg[0];
  float acc[64];
  #pragma unroll
  for (int s = 0; s < 64; s++) acc[s] = 0.0f;
  for (int r = 0; r < 64; r++){
    float v = T1t[(size_t)r * 8192 + p] + T1t[(size_t)(r + 64) * 8192 + p];
    #pragma unroll
    for (int k = 0; k < 16; k++){
      float4 c = ci4[r * 16 + k];
      acc[4*k+0] = fmaf(v, c.x, acc[4*k+0]);
      acc[4*k+1] = fmaf(v, c.y, acc[4*k+1]);
      acc[4*k+2] = fmaf(v, c.z, acc[4*k+2]);
      acc[4*k+3] = fmaf(v, c.w, acc[4*k+3]);
    }
  }
  #pragma unroll
  for (int s = 0; s < 64; s++) Mt[(size_t)s * 8192 + p] = g2 * acc[s];
}

// T2part[hc][r][col] = sum_{c, h in 16-row chunk, w} L[c][h][w] * Mt[r][(c+kk)%2][(h+ii)%64][(w+jj)%64]
__global__ __launch_bounds__(256) void k_conv_T2(const float* __restrict__ Lg,
                                                 const float* __restrict__ Mtg,
                                                 float* __restrict__ T2part){
  __shared__ float Mi[128 * 68];
  __shared__ float4 Ls4[512];
  int r = blockIdx.x, hc = blockIdx.y, tid = threadIdx.x;
  const float4* gm4 = (const float4*)(Mtg + (size_t)r * 8192);
  for (int t = tid; t < 2048; t += 256){
    float4 v4 = gm4[t];
    int row = t >> 4, cb = (t & 15) * 4;
    float* d = &Mi[row * 68 + cb];
    d[0] = v4.x; d[1] = v4.y; d[2] = v4.z; d[3] = v4.w;
  }
  const float4* gl4 = (const float4*)Lg;
  for (int t = tid; t < 512; t += 256){
    int c = t >> 8, rem = t & 255;
    Ls4[t] = gl4[c * 1024 + hc * 256 + rem];
  }
  __syncthreads();
  if (tid >= 216) return;
  int kk = tid / 108, rest = tid % 108, ii = rest / 3, jj0 = (rest % 3) * 12;
  float acc[12];
  #pragma unroll
  for (int u = 0; u < 12; u++) acc[u] = 0.0f;
  #pragma unroll 1
  for (int c = 0; c < 2; c++){
    #pragma unroll 1
    for (int hl = 0; hl < 16; hl++){
      int h = hc * 16 + hl;
      const float* ib = &Mi[(((c + kk) & 1) * 64 + ((h + ii) & 63)) * 68];
      const float4* lrow = &Ls4[c * 256 + hl * 16];
      float v[16];
      {
        float4 t0 = *(const float4*)&ib[jj0];
        float4 t1 = *(const float4*)&ib[jj0 + 4];
        float4 t2 = *(const float4*)&ib[jj0 + 8];
        float4 t3 = *(const float4*)&ib[jj0 + 12];
        v[0]=t0.x; v[1]=t0.y; v[2]=t0.z; v[3]=t0.w;
        v[4]=t1.x; v[5]=t1.y; v[6]=t1.z; v[7]=t1.w;
        v[8]=t2.x; v[9]=t2.y; v[10]=t2.z; v[11]=t2.w;
        v[12]=t3.x; v[13]=t3.y; v[14]=t3.z; v[15]=t3.w;
      }
      #pragma unroll
      for (int wg = 0; wg < 16; wg++){
        float4 lv = lrow[wg];
        #pragma unroll
        for (int u = 0; u < 12; u++) acc[u] = fmaf(lv.x, v[(4*wg + 0 + u) & 15], acc[u]);
        #pragma unroll
        for (int u = 0; u < 12; u++) acc[u] = fmaf(lv.y, v[(4*wg + 1 + u) & 15], acc[u]);
        #pragma unroll
        for (int u = 0; u < 12; u++) acc[u] = fmaf(lv.z, v[(4*wg + 2 + u) & 15], acc[u]);
        #pragma unroll
        for (int u = 0; u < 12; u++) acc[u] = fmaf(lv.w, v[(4*wg + 3 + u) & 15], acc[u]);
        if (wg < 15){
          float4 nv = *(const float4*)&ib[(jj0 + 4*wg + 16) & 63];
          int s = (4*wg) & 15;
          v[s] = nv.x; v[s+1] = nv.y; v[s+2] = nv.z; v[s+3] = nv.w;
        }
      }
    }
  }
  #pragma unroll
  for (int u = 0; u < 12; u++){
    int col = kk * 1296 + (jj0 + u) * 36 + ii;
    T2part[((size_t)hc * 64 + r) * KC + col] = acc[u];
  }
}

// NtT[rr][d(col)] = 2g * sum_s CnInv[s][rr] * T2[s][col];  T2[s][col] = sum_hc T2part[hc][s][col]
__global__ __launch_bounds__(256) void k_nn(const float* __restrict__ T2part, const float* __restrict__ CnInv,
                                            const float* __restrict__ pg,
                                            float* __restrict__ NtT){
  __shared__ float4 ci4[1024];
  int tid = threadIdx.x;
  const float4* g4 = (const float4*)CnInv;
  for (int t = tid; t < 1024; t += 256) ci4[t] = g4[t];
  __syncthreads();
  int col = blockIdx.x * 256 + tid;
  if (col >= KC) return;
  float g2 = 2.0f * pg[0];
  float acc[64];
  #pragma unroll
  for (int rr = 0; rr < 64; rr++) acc[rr] = 0.0f;
  for (int s = 0; s < 64; s++){
    float tv = T2part[(size_t)(0 * 64 + s) * KC + col] + T2part[(size_t)(1 * 64 + s) * KC + col]
             + T2part[(size_t)(2 * 64 + s) * KC + col] + T2part[(size_t)(3 * 64 + s) * KC + col];
    #pragma unroll
    for (int k = 0; k < 16; k++){
      float4 c = ci4[s * 16 + k];
      acc[4*k+0] = fmaf(tv, c.x, acc[4*k+0]);
      acc[4*k+1] = fmaf(tv, c.y, acc[4*k+1]);
      acc[4*k+2] = fmaf(tv, c.z, acc[4*k+2]);
      acc[4*k+3] = fmaf(tv, c.w, acc[4*k+3]);
    }
  }
  int kk = col / 1296, rest = col % 1296, jj = rest / 36, iv = rest % 36;
  int d = (kk * 36 + iv) * 36 + jj;
  #pragma unroll
  for (int rr = 0; rr < 64; rr++){
    NtT[(size_t)rr * KCP + d] = g2 * acc[rr];
  }
}

extern "C" void kernel_launch(void* const* d_in, const int* in_sizes, int n_in,
                              void* d_out, int out_size, void* d_ws, size_t ws_size,
                              hipStream_t stream) {
  const float* inp = (const float*)d_in[0];
  const float* s0  = (const float*)d_in[1];
  const float* pa  = (const float*)d_in[2];
  const float* pb  = (const float*)d_in[3];
  const float* pg  = (const float*)d_in[4];
  float* ws  = (float*)d_ws;
  float* L   = ws + OFF_L;   float* S   = ws + OFF_S;    float* Mt  = ws + OFF_MT;
  float* NtT = ws + OFF_NTT; float* Big = ws + OFF_BIG;
  float* T2p = ws + OFF_T2P; float* Gr  = ws + OFF_GRAM;
  float* CmI = ws + OFF_CMI; float* CnI = ws + OFF_CNI;
  float* out = (float*)d_out;

  k_init<<<2048, 256, 0, stream>>>(inp, s0, L, S, Mt, NtT);
  for (int step = 0; step < 5; step++){
    k_conv_R<<<dim3(64, 8, 2), 128, 0, stream>>>(Mt, NtT, Big);
    bool last = (step == 4);
    k_reduce_LS<<<32, 256, 0, stream>>>(Big, inp, pg, pb, S, last ? out : L);
    if (last) break;
    k_gram<<<4096, 64, 0, stream>>>(NtT, KCP, KCP / 4, Gr);   // Cm raw = N@N^T (pad zeros)
    k_inv<<<1, 256, 0, stream>>>(Gr, pg, pa, CmI);
    k_conv_T1<<<dim3(64, 8, 2), 128, 0, stream>>>(L, NtT, Big);
    k_mn<<<32, 256, 0, stream>>>(Big, CmI, pg, Mt);
    k_gram<<<4096, 64, 0, stream>>>(Mt, 8192, 2048, Gr);      // Cn raw = Mn^T@Mn
    k_inv<<<1, 256, 0, stream>>>(Gr, pg, pa, CnI);
    k_conv_T2<<<dim3(64, 4), 256, 0, stream>>>(L, Mt, T2p);
    k_nn<<<11, 256, 0, stream>>>(T2p, CnI, pg, NtT);
  }
}

// Round 4
// 1156.021 us; speedup vs baseline: 2.8625x; 1.1338x over previous
//
#include <hip/hip_runtime.h>

// Problem constants: B=1, C=2, H=W=64, m=8192, mk=64, K1=K2=36, K3=2, Kc=2592, iters=6 (5 steps).
#define KC 2592
#define KCP 2624           // padded NtT row stride (zeros in tail)
#define HW 4096

// workspace layout (float offsets), total 2818048 floats = 11.27 MB (<= proven 11.29 MB)
#define OFF_L    0u
#define OFF_S    8192u
#define OFF_MT   16384u    // Mt[64][8192]
#define OFF_NTT  540672u   // NtT[64][2624], layout d=(kk*36+ii)*36+jj, cols 2592..2623 zero
#define OFF_BIG  708608u   // Rpart[256][8192] / T1t[256][8192] / (T2part[8][64][2592] + T2sum[64][2592])
#define OFF_GRAM 2805760u  // raw gram 64x64 (shared by Cm and Cn phases)
#define OFF_CMI  2809856u
#define OFF_CNI  2813952u
// inside BIG (disjoint lifetimes): T2P = BIG+0 (1327104), T2SUM = BIG+1327104 (165888)

__global__ __launch_bounds__(256) void k_init(const float* __restrict__ inp, const float* __restrict__ s0,
                                              float* __restrict__ L, float* __restrict__ S,
                                              float* __restrict__ Mt, float* __restrict__ NtT){
  int t = blockIdx.x * 256 + threadIdx.x;
  if (t < 8192){ L[t] = inp[t]; S[t] = s0[t]; }
  if (t < 524288){ int r = t >> 13; int p = t & 8191; Mt[t] = (p == r) ? 1.0f : 0.0f; }
  if (t < 167936){ int r = t / KCP; int d = t - r * KCP;
                   int dr = (r % 36) * 36 + r / 36;   // N0[r][col]=delta(col==r) -> d=(0*36+ii)*36+jj, col=jj*36+ii=r
                   NtT[t] = (d == dr) ? 1.0f : 0.0f; }
}

// ---- conv_R: Rpart[r+64z][p] = sum_{kk, ii in quarter z, jj} Mt[r][(c+kk)%2][(h+ii)%64][(w+jj)%64] * f[kk][ii][jj]
__global__ __launch_bounds__(128) void k_conv_R(const float* __restrict__ Mtg,
                                                const float* __restrict__ NtT,
                                                float* __restrict__ Rpart){
  __shared__ float img[128 * 68];
  __shared__ float4 filt4[162];
  int r = blockIdx.x, oct = blockIdx.y, z = blockIdx.z, tid = threadIdx.x;
  const float4* gi4 = (const float4*)(Mtg + (size_t)r * 8192);
  for (int t = tid; t < 2048; t += 128){
    float4 v4 = gi4[t];
    int row = t >> 4, cb = (t & 15) * 4;
    float* d = &img[row * 68 + cb];
    d[0] = v4.x; d[1] = v4.y; d[2] = v4.z; d[3] = v4.w;
  }
  int iilo = z * 9;
  const float* gf = NtT + (size_t)r * KCP;
  for (int t = tid; t < 162; t += 128){
    int kk = t / 81; int rem4 = t - kk * 81;
    filt4[t] = *(const float4*)(gf + kk * 1296 + iilo * 36 + rem4 * 4);
  }
  __syncthreads();
  int c0 = tid >> 6, hloc = (tid >> 3) & 7, w0 = (tid & 7) * 8;
  int h = oct * 8 + hloc;
  float acc[8] = {0,0,0,0,0,0,0,0};
  #pragma unroll 1
  for (int kk = 0; kk < 2; kk++){
    int crow = ((c0 + kk) & 1) << 6;
    #pragma unroll 1
    for (int iix = 0; iix < 9; iix++){
      int ii = iilo + iix;
      const float* ib = &img[(crow + ((h + ii) & 63)) * 68];
      float v[16];
      {
        float4 t0 = *(const float4*)&ib[w0];
        float4 t1 = *(const float4*)&ib[(w0 + 4) & 63];
        float4 t2 = *(const float4*)&ib[(w0 + 8) & 63];
        float4 t3 = *(const float4*)&ib[(w0 + 12) & 63];
        v[0]=t0.x; v[1]=t0.y; v[2]=t0.z; v[3]=t0.w;
        v[4]=t1.x; v[5]=t1.y; v[6]=t1.z; v[7]=t1.w;
        v[8]=t2.x; v[9]=t2.y; v[10]=t2.z; v[11]=t2.w;
        v[12]=t3.x; v[13]=t3.y; v[14]=t3.z; v[15]=t3.w;
      }
      const float4* fb = &filt4[kk * 81 + iix * 9];
      #pragma unroll
      for (int g = 0; g < 9; g++){
        float4 ff = fb[g];
        #pragma unroll
        for (int u = 0; u < 8; u++) acc[u] = fmaf(ff.x, v[(u + 4*g + 0) & 15], acc[u]);
        #pragma unroll
        for (int u = 0; u < 8; u++) acc[u] = fmaf(ff.y, v[(u + 4*g + 1) & 15], acc[u]);
        #pragma unroll
        for (int u = 0; u < 8; u++) acc[u] = fmaf(ff.z, v[(u + 4*g + 2) & 15], acc[u]);
        #pragma unroll
        for (int u = 0; u < 8; u++) acc[u] = fmaf(ff.w, v[(u + 4*g + 3) & 15], acc[u]);
        if (g < 7){
          float4 nv = *(const float4*)&ib[(w0 + 16 + 4*g) & 63];
          int s = (4*g) & 15;
          v[s] = nv.x; v[s+1] = nv.y; v[s+2] = nv.z; v[s+3] = nv.w;
        }
      }
    }
  }
  size_t ob = ((size_t)r + 64 * z) * 8192 + (size_t)(c0 * HW + h * 64 + w0);
  *(float4*)&Rpart[ob]     = make_float4(acc[0], acc[1], acc[2], acc[3]);
  *(float4*)&Rpart[ob + 4] = make_float4(acc[4], acc[5], acc[6], acc[7]);
}

// ---- conv_T1: T1t[r+64z][p] = sum L[(c-kk)%2][(h-ii)%64][(w-jj)%64] * f[kk][ii][jj]
__global__ __launch_bounds__(128) void k_conv_T1(const float* __restrict__ Lg,
                                                 const float* __restrict__ NtT,
                                                 float* __restrict__ T1t){
  __shared__ float img[128 * 68];
  __shared__ float4 filt4[162];
  int r = blockIdx.x, oct = blockIdx.y, z = blockIdx.z, tid = threadIdx.x;
  const float4* gi4 = (const float4*)Lg;
  for (int t = tid; t < 2048; t += 128){
    float4 v4 = gi4[t];
    int row = t >> 4, cb = (t & 15) * 4;
    float* d = &img[row * 68 + cb];
    d[0] = v4.x; d[1] = v4.y; d[2] = v4.z; d[3] = v4.w;
  }
  int iilo = z * 9;
  const float* gf = NtT + (size_t)r * KCP;
  for (int t = tid; t < 162; t += 128){
    int kk = t / 81; int rem4 = t - kk * 81;
    filt4[t] = *(const float4*)(gf + kk * 1296 + iilo * 36 + rem4 * 4);
  }
  __syncthreads();
  int c0 = tid >> 6, hloc = (tid >> 3) & 7, w0 = (tid & 7) * 8;
  int h = oct * 8 + hloc;
  float acc[8] = {0,0,0,0,0,0,0,0};
  #pragma unroll 1
  for (int kk = 0; kk < 2; kk++){
    int crow = ((c0 - kk + 2) & 1) << 6;
    #pragma unroll 1
    for (int iix = 0; iix < 9; iix++){
      int ii = iilo + iix;
      const float* ib = &img[(crow + ((h - ii + 64) & 63)) * 68];
      float v[16];
      {
        float4 t0 = *(const float4*)&ib[(w0 - 8 + 64) & 63];
        float4 t1 = *(const float4*)&ib[(w0 - 4 + 64) & 63];
        float4 t2 = *(const float4*)&ib[w0];
        float4 t3 = *(const float4*)&ib[(w0 + 4) & 63];
        v[8]=t0.x;  v[9]=t0.y;  v[10]=t0.z; v[11]=t0.w;
        v[12]=t1.x; v[13]=t1.y; v[14]=t1.z; v[15]=t1.w;
        v[0]=t2.x;  v[1]=t2.y;  v[2]=t2.z;  v[3]=t2.w;
        v[4]=t3.x;  v[5]=t3.y;  v[6]=t3.z;  v[7]=t3.w;
      }
      const float4* fb = &filt4[kk * 81 + iix * 9];
      #pragma unroll
      for (int g = 0; g < 9; g++){
        float4 ff = fb[g];
        #pragma unroll
        for (int u = 0; u < 8; u++) acc[u] = fmaf(ff.x, v[(u - (4*g + 0)) & 15], acc[u]);
        #pragma unroll
        for (int u = 0; u < 8; u++) acc[u] = fmaf(ff.y, v[(u - (4*g + 1)) & 15], acc[u]);
        #pragma unroll
        for (int u = 0; u < 8; u++) acc[u] = fmaf(ff.z, v[(u - (4*g + 2)) & 15], acc[u]);
        #pragma unroll
        for (int u = 0; u < 8; u++) acc[u] = fmaf(ff.w, v[(u - (4*g + 3)) & 15], acc[u]);
        if (g < 7){
          float4 nv = *(const float4*)&ib[(w0 - 4*g - 12 + 64) & 63];
          int s = (4 - 4*g) & 15;
          v[s] = nv.x; v[s+1] = nv.y; v[s+2] = nv.z; v[s+3] = nv.w;
        }
      }
    }
  }
  size_t ob = ((size_t)r + 64 * z) * 8192 + (size_t)(c0 * HW + h * 64 + w0);
  *(float4*)&T1t[ob]     = make_float4(acc[0], acc[1], acc[2], acc[3]);
  *(float4*)&T1t[ob + 4] = make_float4(acc[4], acc[5], acc[6], acc[7]);
}

// L[p] = clip((inp - S + g*R)/(g+1)); S = (inp - L)/(b+1); R = (1/Kc) * sum_{256 slices} Rpart
__global__ __launch_bounds__(256) void k_reduce_LS(const float* __restrict__ Rpart,
                                                   const float* __restrict__ inp,
                                                   const float* __restrict__ pg, const float* __restrict__ pb,
                                                   float* __restrict__ S, float* __restrict__ Ldst){
  int p = blockIdx.x * 256 + threadIdx.x;
  float acc = 0.0f;
  for (int r = 0; r < 256; r++) acc += Rpart[(size_t)r * 8192 + p];
  float R = acc * (1.0f / 2592.0f);
  float g = pg[0], b = pb[0];
  float Ln = (inp[p] - S[p] + g * R) / (g + 1.0f);
  Ln = fminf(fmaxf(Ln, 0.0f), 1.0f);
  S[p] = (inp[p] - Ln) / (b + 1.0f);
  Ldst[p] = Ln;
}

// raw gram: out[r1][r2] = dot(rows[r1], rows[r2]) over len4 float4s (row stride in floats)
__global__ __launch_bounds__(64) void k_gram(const float* __restrict__ rows, int stride, int len4,
                                             float* __restrict__ out){
  int e = blockIdx.x; int r1 = e >> 6, r2 = e & 63;
  if (r2 < r1) return;
  int lane = threadIdx.x;
  const float4* a = (const float4*)(rows + (size_t)r1 * stride);
  const float4* b = (const float4*)(rows + (size_t)r2 * stride);
  float acc = 0.0f;
  for (int p = lane; p < len4; p += 64){
    float4 x = a[p], y = b[p];
    acc = fmaf(x.x, y.x, acc); acc = fmaf(x.y, y.y, acc);
    acc = fmaf(x.z, y.z, acc); acc = fmaf(x.w, y.w, acc);
  }
  for (int off = 32; off; off >>= 1) acc += __shfl_down(acc, off, 64);
  if (lane == 0){ out[r1 * 64 + r2] = acc; out[r2 * 64 + r1] = acc; }
}

// dst = inv( 2*g*gram + a*I ), register-resident Gauss-Jordan (SPD, no pivoting)
__global__ __launch_bounds__(256) void k_inv(const float* __restrict__ src,
                                             const float* __restrict__ pg, const float* __restrict__ pa,
                                             float* __restrict__ dst){
  __shared__ float rowbuf[128];
  __shared__ float fcol[64];
  int tid = threadIdx.x;
  int i = tid >> 2, c4 = tid & 3;
  float scale = 2.0f * pg[0];
  float ad = pa[0];
  float a[32];
  #pragma unroll
  for (int k = 0; k < 16; k++){
    int col = c4 + 4 * k;
    a[k] = scale * src[i * 64 + col] + ((i == col) ? ad : 0.0f);
  }
  #pragma unroll
  for (int k = 16; k < 32; k++){
    int col = c4 + 4 * k - 64;
    a[k] = (i == col) ? 1.0f : 0.0f;
  }
  #pragma unroll
  for (int j = 0; j < 64; j++){
    if (c4 == (j & 3)) fcol[i] = a[j >> 2];
    if (i == j){
      #pragma unroll
      for (int k = 0; k < 32; k++) rowbuf[c4 + 4 * k] = a[k];
    }
    __syncthreads();
    float fj = fcol[i];
    float pivinv = 1.0f / fcol[j];
    float t = fj * pivinv;
    #pragma unroll
    for (int k = 0; k < 32; k++){
      float rv = rowbuf[c4 + 4 * k];
      a[k] = (i == j) ? (rv * pivinv) : fmaf(-t, rv, a[k]);
    }
    __syncthreads();
  }
  #pragma unroll
  for (int k = 16; k < 32; k++){
    int col = c4 + 4 * k - 64;
    dst[i * 64 + col] = a[k];
  }
}

// Mt_new[sbase+s][p] = 2g * sum_{r<64} (sum_z T1t[r+64z][p]) * CmInv[r][sbase+s]
__global__ __launch_bounds__(256) void k_mn(const float* __restrict__ T1t, const float* __restrict__ CmInv,
                                            const float* __restrict__ pg, float* __restrict__ Mt){
  __shared__ float4 ci4[1024];
  int tid = threadIdx.x;
  const float4* g4 = (const float4*)CmInv;
  for (int t = tid; t < 1024; t += 256) ci4[t] = g4[t];
  __syncthreads();
  int p = blockIdx.x * 256 + tid;
  int sbase = blockIdx.y * 32;
  float g2 = 2.0f * pg[0];
  float acc[32];
  #pragma unroll
  for (int s = 0; s < 32; s++) acc[s] = 0.0f;
  for (int r = 0; r < 64; r++){
    float v = T1t[(size_t)r * 8192 + p] + T1t[(size_t)(r + 64) * 8192 + p]
            + T1t[(size_t)(r + 128) * 8192 + p] + T1t[(size_t)(r + 192) * 8192 + p];
    #pragma unroll
    for (int k = 0; k < 8; k++){
      float4 c = ci4[r * 16 + (sbase >> 2) + k];
      acc[4*k+0] = fmaf(v, c.x, acc[4*k+0]);
      acc[4*k+1] = fmaf(v, c.y, acc[4*k+1]);
      acc[4*k+2] = fmaf(v, c.z, acc[4*k+2]);
      acc[4*k+3] = fmaf(v, c.w, acc[4*k+3]);
    }
  }
  #pragma unroll
  for (int s = 0; s < 32; s++) Mt[(size_t)(sbase + s) * 8192 + p] = g2 * acc[s];
}

// T2part[hc][r][col] = sum_{c, h in 8-row chunk hc, w} L[c][h][w] * Mt[r][(c+kk)%2][(h+ii)%64][(w+jj)%64]
__global__ __launch_bounds__(256) void k_conv_T2(const float* __restrict__ Lg,
                                                 const float* __restrict__ Mtg,
                                                 float* __restrict__ T2part){
  __shared__ float Mi[128 * 68];
  __shared__ float4 Ls4[256];
  int r = blockIdx.x, hc = blockIdx.y, tid = threadIdx.x;
  const float4* gm4 = (const float4*)(Mtg + (size_t)r * 8192);
  for (int t = tid; t < 2048; t += 256){
    float4 v4 = gm4[t];
    int row = t >> 4, cb = (t & 15) * 4;
    float* d = &Mi[row * 68 + cb];
    d[0] = v4.x; d[1] = v4.y; d[2] = v4.z; d[3] = v4.w;
  }
  const float4* gl4 = (const float4*)Lg;
  if (tid < 256){
    int c = tid >> 7, rem = tid & 127;
    Ls4[tid] = gl4[c * 1024 + hc * 128 + rem];
  }
  __syncthreads();
  if (tid >= 216) return;
  int kk = tid / 108, rest = tid % 108, ii = rest / 3, jj0 = (rest % 3) * 12;
  float acc[12];
  #pragma unroll
  for (int u = 0; u < 12; u++) acc[u] = 0.0f;
  #pragma unroll 1
  for (int c = 0; c < 2; c++){
    #pragma unroll 1
    for (int hl = 0; hl < 8; hl++){
      int h = hc * 8 + hl;
      const float* ib = &Mi[(((c + kk) & 1) * 64 + ((h + ii) & 63)) * 68];
      const float4* lrow = &Ls4[c * 128 + hl * 16];
      float v[16];
      {
        float4 t0 = *(const float4*)&ib[jj0];
        float4 t1 = *(const float4*)&ib[jj0 + 4];
        float4 t2 = *(const float4*)&ib[jj0 + 8];
        float4 t3 = *(const float4*)&ib[jj0 + 12];
        v[0]=t0.x; v[1]=t0.y; v[2]=t0.z; v[3]=t0.w;
        v[4]=t1.x; v[5]=t1.y; v[6]=t1.z; v[7]=t1.w;
        v[8]=t2.x; v[9]=t2.y; v[10]=t2.z; v[11]=t2.w;
        v[12]=t3.x; v[13]=t3.y; v[14]=t3.z; v[15]=t3.w;
      }
      #pragma unroll
      for (int wg = 0; wg < 16; wg++){
        float4 lv = lrow[wg];
        #pragma unroll
        for (int u = 0; u < 12; u++) acc[u] = fmaf(lv.x, v[(4*wg + 0 + u) & 15], acc[u]);
        #pragma unroll
        for (int u = 0; u < 12; u++) acc[u] = fmaf(lv.y, v[(4*wg + 1 + u) & 15], acc[u]);
        #pragma unroll
        for (int u = 0; u < 12; u++) acc[u] = fmaf(lv.z, v[(4*wg + 2 + u) & 15], acc[u]);
        #pragma unroll
        for (int u = 0; u < 12; u++) acc[u] = fmaf(lv.w, v[(4*wg + 3 + u) & 15], acc[u]);
        if (wg < 15){
          float4 nv = *(const float4*)&ib[(jj0 + 4*wg + 16) & 63];
          int s = (4*wg) & 15;
          v[s] = nv.x; v[s+1] = nv.y; v[s+2] = nv.z; v[s+3] = nv.w;
        }
      }
    }
  }
  #pragma unroll
  for (int u = 0; u < 12; u++){
    int col = kk * 1296 + (jj0 + u) * 36 + ii;
    T2part[((size_t)hc * 64 + r) * KC + col] = acc[u];
  }
}

// T2sum[t] = sum_hc T2part[hc*165888 + t]   (t = r*KC+col)
__global__ __launch_bounds__(256) void k_t2sum(const float* __restrict__ T2part, float* __restrict__ T2sum){
  int t = blockIdx.x * 256 + threadIdx.x;
  float s = 0.0f;
  #pragma unroll
  for (int hc = 0; hc < 8; hc++) s += T2part[(size_t)hc * 165888 + t];
  T2sum[t] = s;
}

// NtT[rr][d(col)] = 2g * sum_s CnInv[s][rr] * T2sum[s][col], rr in 16-chunk per blockIdx.y
__global__ __launch_bounds__(256) void k_nn(const float* __restrict__ T2sum, const float* __restrict__ CnInv,
                                            const float* __restrict__ pg,
                                            float* __restrict__ NtT){
  __shared__ float4 ci4[1024];
  int tid = threadIdx.x;
  const float4* g4 = (const float4*)CnInv;
  for (int t = tid; t < 1024; t += 256) ci4[t] = g4[t];
  __syncthreads();
  int col = blockIdx.x * 256 + tid;
  if (col >= KC) return;
  int rb = blockIdx.y * 16;
  float g2 = 2.0f * pg[0];
  float acc[16];
  #pragma unroll
  for (int rr = 0; rr < 16; rr++) acc[rr] = 0.0f;
  for (int s = 0; s < 64; s++){
    float tv = T2sum[(size_t)s * KC + col];
    #pragma unroll
    for (int k = 0; k < 4; k++){
      float4 c = ci4[s * 16 + (rb >> 2) + k];
      acc[4*k+0] = fmaf(tv, c.x, acc[4*k+0]);
      acc[4*k+1] = fmaf(tv, c.y, acc[4*k+1]);
      acc[4*k+2] = fmaf(tv, c.z, acc[4*k+2]);
      acc[4*k+3] = fmaf(tv, c.w, acc[4*k+3]);
    }
  }
  int kk = col / 1296, rest = col % 1296, jj = rest / 36, iv = rest % 36;
  int d = (kk * 36 + iv) * 36 + jj;
  #pragma unroll
  for (int rr = 0; rr < 16; rr++){
    NtT[(size_t)(rb + rr) * KCP + d] = g2 * acc[rr];
  }
}

extern "C" void kernel_launch(void* const* d_in, const int* in_sizes, int n_in,
                              void* d_out, int out_size, void* d_ws, size_t ws_size,
                              hipStream_t stream) {
  const float* inp = (const float*)d_in[0];
  const float* s0  = (const float*)d_in[1];
  const float* pa  = (const float*)d_in[2];
  const float* pb  = (const float*)d_in[3];
  const float* pg  = (const float*)d_in[4];
  float* ws  = (float*)d_ws;
  float* L   = ws + OFF_L;   float* S   = ws + OFF_S;    float* Mt  = ws + OFF_MT;
  float* NtT = ws + OFF_NTT; float* Big = ws + OFF_BIG;
  float* T2p = ws + OFF_BIG;              // aliased into Big (disjoint lifetimes)
  float* T2s = ws + OFF_BIG + 1327104u;   // aliased into Big
  float* Gr  = ws + OFF_GRAM;
  float* CmI = ws + OFF_CMI; float* CnI = ws + OFF_CNI;
  float* out = (float*)d_out;

  k_init<<<2048, 256, 0, stream>>>(inp, s0, L, S, Mt, NtT);
  for (int step = 0; step < 5; step++){
    k_conv_R<<<dim3(64, 8, 4), 128, 0, stream>>>(Mt, NtT, Big);
    bool last = (step == 4);
    k_reduce_LS<<<32, 256, 0, stream>>>(Big, inp, pg, pb, S, last ? out : L);
    if (last) break;
    k_gram<<<4096, 64, 0, stream>>>(NtT, KCP, KCP / 4, Gr);   // Cm raw = N@N^T (pad zeros)
    k_inv<<<1, 256, 0, stream>>>(Gr, pg, pa, CmI);
    k_conv_T1<<<dim3(64, 8, 4), 128, 0, stream>>>(L, NtT, Big);
    k_mn<<<dim3(32, 2), 256, 0, stream>>>(Big, CmI, pg, Mt);
    k_gram<<<4096, 64, 0, stream>>>(Mt, 8192, 2048, Gr);      // Cn raw = Mn^T@Mn
    k_inv<<<1, 256, 0, stream>>>(Gr, pg, pa, CnI);
    k_conv_T2<<<dim3(64, 8), 256, 0, stream>>>(L, Mt, T2p);
    k_t2sum<<<648, 256, 0, stream>>>(T2p, T2s);
    k_nn<<<dim3(11, 4), 256, 0, stream>>>(T2s, CnI, pg, NtT);
  }
}